// Round 8
// baseline (691.991 us; speedup 1.0000x reference)
//
#include <hip/hip_runtime.h>
#include <math.h>

// Problem constants
constexpr int B = 32, T = 2048, P = 128, K = 256, R = 8, M = 64;
constexpr int BT = B * T;                 // 65536 rows
constexpr int TAU = 5;
constexpr int NSEG = (T + TAU - 1) / TAU; // 410 segments
constexpr float INV_TAU_X = 1.0f / 100.0f;
constexpr float INV_TAU_Z = 1.0f / 100.0f;

typedef short bf16x4 __attribute__((ext_vector_type(4)));
typedef short bf16x8 __attribute__((ext_vector_type(8)));
typedef float f32x4 __attribute__((ext_vector_type(4)));

// fp32 <-> bf16 (RNE)
static __device__ __forceinline__ short f2bf(float f) {
  unsigned u = __builtin_bit_cast(unsigned, f);
  u += 0x7FFF + ((u >> 16) & 1);
  return (short)(u >> 16);
}
static __device__ __forceinline__ float bf2f(short h) {
  unsigned u = ((unsigned)(unsigned short)h) << 16;
  return __builtin_bit_cast(float, u);
}

// fast transcendentals (v_exp + v_rcp, ~1e-6 rel — invisible vs 2e-2 thresh)
static __device__ __forceinline__ float tanh_fast(float x) {
  const float e = __expf(2.f * x);
  return 1.f - 2.f * __builtin_amdgcn_rcpf(e + 1.f);
}
static __device__ __forceinline__ float sigmoid_fast(float x) {
  return __builtin_amdgcn_rcpf(1.f + __expf(-x));
}

// ---------------------------------------------------------------------------
// 64-lane all-reduce (sum) for 8 values. Stages 1-4 are the rocPRIM-standard
// gfx9 DPP ladder (all-VALU); stage 5 = ds_swizzle 0x401F (xor16), stage 6 =
// __shfl_xor 32. NOTE: gfx950 permlane16/32_swap builtins produced wrong
// sums here (r1 fail) — semantics differ from the assumed two-reg swap.
// ---------------------------------------------------------------------------
template <int CTRL>
static __device__ __forceinline__ float dppadd(float p) {
  return p + __builtin_bit_cast(
                 float, __builtin_amdgcn_update_dpp(
                            0, __builtin_bit_cast(int, p), CTRL, 0xF, 0xF, true));
}

static __device__ __forceinline__ void allreduce8(float p[R]) {
#pragma unroll
  for (int r = 0; r < R; ++r) p[r] = dppadd<0xB1>(p[r]);   // quad_perm [1,0,3,2]
#pragma unroll
  for (int r = 0; r < R; ++r) p[r] = dppadd<0x4E>(p[r]);   // quad_perm [2,3,0,1]
#pragma unroll
  for (int r = 0; r < R; ++r) p[r] = dppadd<0x141>(p[r]);  // row_half_mirror
#pragma unroll
  for (int r = 0; r < R; ++r) p[r] = dppadd<0x140>(p[r]);  // row_mirror
#pragma unroll
  for (int r = 0; r < R; ++r)                              // xor 16 (in-half)
    p[r] += __builtin_bit_cast(float, __builtin_amdgcn_ds_swizzle(
                                          __builtin_bit_cast(int, p[r]), 0x401F));
#pragma unroll
  for (int r = 0; r < R; ++r)                              // xor 32 (cross-half)
    p[r] += __shfl_xor(p[r], 32, 64);
}

// Batched split of the 8 weight matrices into one region: weight w's hi at
// dst+hoff[w], lo at dst+hoff[w]+4*n4[w].
struct W8 {
  const float* src[8];
  unsigned hoff[8];  // in shorts
  unsigned n4[8];
};
__global__ __launch_bounds__(256) void split8_kernel(W8 p, short* __restrict__ dst) {
  const int w = blockIdx.y;
  const int i = blockIdx.x * 256 + threadIdx.x;
  if (i >= (int)p.n4[w]) return;
  const float4 v = ((const float4*)p.src[w])[i];
  const float f[4] = {v.x, v.y, v.z, v.w};
  bf16x4 ph, pl;
#pragma unroll
  for (int q = 0; q < 4; ++q) {
    ph[q] = f2bf(f[q]);
    pl[q] = f2bf(f[q] - bf2f(ph[q]));
  }
  *(bf16x4*)&dst[p.hoff[w] + i * 4] = ph;
  *(bf16x4*)&dst[p.hoff[w] + p.n4[w] * 4 + i * 4] = pl;
}

// ---------------------------------------------------------------------------
// r8 (= r7 resubmit; r7's bench was an infra failure, kernel never ran).
// FUSED MLP CHAIN. One kernel runs up to 5 layers of
// C = tanh(A @ W^T + b) for a 128-row strip, with intermediates living
// entirely in LDS (fp32, in-place buffer reuse across layers) and weights
// read register-direct from L2 (split-bf16 blob, <=1.1 MB resident).
// This removes every intermediate HBM round-trip (the 10-GEMM pipeline was
// ~1 GB of HBM traffic vs ~140 GFLOP of MFMA work).
//
//  - 8 waves (512 thr), wave grid 4Mx2N: wave owns rows wm*32..+31 and the
//    cg half of the output columns. Per k-tile: A frags from LDS (fp32,
//    split to bf16 h/l in-reg exactly like split_kernel), B frags h/l from
//    L2 (same address pattern as r5/r6). 3 MFMAs (hh,lh,hl) per acc, k0
//    ascending -> bit-identical results to the unfused version.
//  - NO barriers inside the k-loop (compiler pipelines the L2 B loads);
//    exactly 2 barriers per layer boundary: MFMA-done -> epilogue-write,
//    write-done -> next-layer reads. Last layer writes global only.
//  - LDS buffer [128][W] fp32, XOR-swizzled at 8-float (32 B) chunks:
//    slot = chunk ^ (row & 7), applied identically at staging, A-frag
//    reads, and epilogue writes (both-sides-or-neither rule). In-place
//    width change per layer is safe: A is fully consumed before the
//    barrier that precedes C writes.
//  - Max width 256 -> 128 KiB static LDS (HW-proven on gfx950: the learn
//    loop's 256^2 8-phase template uses exactly this), 1 block/CU.
//  - All __syncthreads() are on wave-uniform paths (constexpr layer
//    structure; `if (gout)` is uniform) -> no divergent-barrier hazard.
// ---------------------------------------------------------------------------
struct FusedArgs {
  const float* A0;       // global input, width K0, BT rows
  const short* Wh[5];    // split weights (hi)
  const short* Wl[5];    // split weights (lo)
  const float* bias[5];
  float* gout[5];        // optional global output per layer (nullptr = none)
};

template <int I> struct Ly { static constexpr int v = I; };

template <int MAXW, int NL, int K0, int K1, int K2, int K3, int K4, int K5>
__global__ __launch_bounds__(512) void fused_mlp(FusedArgs p) {
  constexpr int Kd[6] = {K0, K1, K2, K3, K4, K5};
  __shared__ float buf[128 * MAXW];

  const int tid = threadIdx.x;
  const int wave = tid >> 6, lane = tid & 63;
  const int l16 = lane & 15, quad = lane >> 4;
  const int wm = wave >> 1, cg = wave & 1;
  const int row0 = blockIdx.x * 128;

  // stage layer-0 input rows into LDS (32 B chunks, swizzled slot = ch^(row&7))
  constexpr int CH0 = K0 / 8;
  for (int c = tid; c < 128 * CH0; c += 512) {
    const int row = c / CH0, ch = c % CH0;
    const float* g = p.A0 + (size_t)(row0 + row) * K0 + ch * 8;
    const f32x4 v0 = *(const f32x4*)g;
    const f32x4 v1 = *(const f32x4*)(g + 4);
    const int cc = ch ^ (row & 7);
    *(f32x4*)&buf[row * K0 + cc * 8] = v0;
    *(f32x4*)&buf[row * K0 + cc * 8 + 4] = v1;
  }
  __syncthreads();

  auto do_layer = [&](auto lc) {
    constexpr int l = decltype(lc)::v;
    constexpr int KIN = Kd[l], KOUT = Kd[l + 1];
    constexpr int JT = KOUT / 32;   // 16-col tiles per wave (half-width)
    constexpr int NKT = KIN / 32;   // k tiles
    const int cols0w = cg * (KOUT / 2);

    f32x4 acc[2][JT];
#pragma unroll
    for (int i = 0; i < 2; ++i)
#pragma unroll
      for (int j = 0; j < JT; ++j) acc[i][j] = (f32x4){0.f, 0.f, 0.f, 0.f};

    for (int kt = 0; kt < NKT; ++kt) {
      bf16x8 ah[2], al[2];
#pragma unroll
      for (int i = 0; i < 2; ++i) {
        const int rowr = wm * 32 + i * 16 + l16;
        const int cc = (kt * 4 + quad) ^ (rowr & 7);
        const f32x4 a0 = *(const f32x4*)&buf[rowr * KIN + cc * 8];
        const f32x4 a1 = *(const f32x4*)&buf[rowr * KIN + cc * 8 + 4];
#pragma unroll
        for (int e = 0; e < 4; ++e) {
          ah[i][e] = f2bf(a0[e]);
          al[i][e] = f2bf(a0[e] - bf2f(ah[i][e]));
          ah[i][4 + e] = f2bf(a1[e]);
          al[i][4 + e] = f2bf(a1[e] - bf2f(ah[i][4 + e]));
        }
      }
#pragma unroll
      for (int j = 0; j < JT; ++j) {
        const size_t boff =
            (size_t)(cols0w + j * 16 + l16) * KIN + kt * 32 + quad * 8;
        const bf16x8 bh = *(const bf16x8*)(p.Wh[l] + boff);
        const bf16x8 bl = *(const bf16x8*)(p.Wl[l] + boff);
#pragma unroll
        for (int i = 0; i < 2; ++i) {
          acc[i][j] = __builtin_amdgcn_mfma_f32_16x16x32_bf16(ah[i], bh,
                                                              acc[i][j], 0, 0, 0);
          acc[i][j] = __builtin_amdgcn_mfma_f32_16x16x32_bf16(al[i], bh,
                                                              acc[i][j], 0, 0, 0);
          acc[i][j] = __builtin_amdgcn_mfma_f32_16x16x32_bf16(ah[i], bl,
                                                              acc[i][j], 0, 0, 0);
        }
      }
    }
    if constexpr (l < NL - 1) __syncthreads();  // all A reads done

    // epilogue: tanh -> LDS (next A) and/or global
    float* gout = p.gout[l];
#pragma unroll
    for (int j = 0; j < JT; ++j) {
      const int col = cols0w + j * 16 + l16;
      const float bj = p.bias[l][col];
#pragma unroll
      for (int i = 0; i < 2; ++i) {
#pragma unroll
        for (int r = 0; r < 4; ++r) {
          const float v = tanh_fast(acc[i][j][r] + bj);
          const int row = wm * 32 + i * 16 + quad * 4 + r;
          if constexpr (l < NL - 1) {
            const int cw = col >> 3;
            buf[row * KOUT + ((cw ^ (row & 7)) << 3) + (col & 7)] = v;
          }
          if (gout) gout[(size_t)(row0 + row) * KOUT + col] = v;
        }
      }
    }
    if constexpr (l < NL - 1) __syncthreads();  // next A ready
  };

  do_layer(Ly<0>{});
  if constexpr (NL > 1) do_layer(Ly<1>{});
  if constexpr (NL > 2) do_layer(Ly<2>{});
  if constexpr (NL > 3) do_layer(Ly<3>{});
  if constexpr (NL > 4) do_layer(Ly<4>{});
}

// ---------------------------------------------------------------------------
// Scan: unchanged from r6 (proven, ~78 µs). Reset every TAU=5 -> independent
// (batch, segment) chains; one wave per chain, 8 waves/block, no inner
// barriers. fp32 x in-place on X0.
// ---------------------------------------------------------------------------
__global__ __launch_bounds__(512) void scan_kernel(
    float* xs,                                 // fp32 x_seq / x_states (in-place)
    const float* __restrict__ z_seq,           // fp32
    const float* __restrict__ Lm, const float* __restrict__ Rm,
    const float* __restrict__ Wz, const float* __restrict__ Az_w,
    const float* __restrict__ Az_b,
    float* __restrict__ z_pred) {
  __shared__ __align__(16) float Wz_s[M][68];  // stride 68: 16B rows, balanced
  __shared__ __align__(16) float Ls[K * R];    // native [k][r] layout
  __shared__ __align__(16) float Rs[K * R];    // native [k][r] layout
  __shared__ __align__(16) float tz_s[8][M];   // per-wave rows (256 B aligned)

  const int tid = threadIdx.x;
  for (int i = tid; i < M * M; i += 512) Wz_s[i >> 6][i & 63] = Wz[i];
  // K*R = 2048 floats = 512 float4 -> exactly one per thread
  ((float4*)Ls)[tid] = ((const float4*)Lm)[tid];
  ((float4*)Rs)[tid] = ((const float4*)Rm)[tid];
  __syncthreads();

  const int wave = tid >> 6;
  const int lane = tid & 63;
  const int chain = blockIdx.x * 8 + wave;
  const int b = chain / NSEG;
  const int seg = chain % NSEG;
  const int t0 = seg * TAU;

  // per-lane register caches (reused all 5 steps)
  float azw[R], azb[R];
#pragma unroll
  for (int r = 0; r < R; ++r) {
    azw[r] = Az_w[r * M + lane];
    azb[r] = Az_b[r];
  }

  float x[4], z;
  {
    const size_t base = ((size_t)b * T + t0);
#pragma unroll
    for (int j = 0; j < 4; ++j) x[j] = xs[base * K + lane + 64 * j];
    z = z_seq[base * M + lane];
  }

  const float4* wrow = (const float4*)&Wz_s[lane][0];  // lane*272 B, 16-al.
  const float4* trow = (const float4*)&tz_s[wave][0];

  for (int tt = 0; tt < TAU; ++tt) {
    const int t = t0 + tt;
    // z update: z += (tanh(z) @ Wz^T - z)/100
    const float tz = tanh_fast(z);
    tz_s[wave][lane] = tz;  // wave-private row; intra-wave DS order suffices
    float zacc = 0.f;
#pragma unroll
    for (int j = 0; j < 16; ++j) {
      const float4 w = wrow[j], tv = trow[j];
      zacc += w.x * tv.x + w.y * tv.y + w.z * tv.z + w.w * tv.w;
    }
    const float znew = z + (zacc - z) * INV_TAU_Z;

    // s = sigmoid(z_new @ Az^T + b)  — DPP/swizzle butterfly reduce
    float s[R];
#pragma unroll
    for (int r = 0; r < R; ++r) s[r] = znew * azw[r];
    allreduce8(s);
#pragma unroll
    for (int r = 0; r < R; ++r) s[r] = sigmoid_fast(s[r] + azb[r]);

    // x update: u = tanh(x) @ L ; v = u*s ; x += (v @ Rm^T - x)/100
    float tx4[4];
#pragma unroll
    for (int j = 0; j < 4; ++j) tx4[j] = tanh_fast(x[j]);
    float v[R];
#pragma unroll
    for (int r = 0; r < R; ++r) v[r] = 0.f;
#pragma unroll
    for (int j = 0; j < 4; ++j) {
      const int kb = (lane + 64 * j) * 8;
      const f32x4 la = *(const f32x4*)&Ls[kb];
      const f32x4 lb = *(const f32x4*)&Ls[kb + 4];
      const float txj = tx4[j];
      v[0] += txj * la[0]; v[1] += txj * la[1];
      v[2] += txj * la[2]; v[3] += txj * la[3];
      v[4] += txj * lb[0]; v[5] += txj * lb[1];
      v[6] += txj * lb[2]; v[7] += txj * lb[3];
    }
    allreduce8(v);
#pragma unroll
    for (int r = 0; r < R; ++r) v[r] *= s[r];
#pragma unroll
    for (int j = 0; j < 4; ++j) {
      const int kb = (lane + 64 * j) * 8;
      const f32x4 ra = *(const f32x4*)&Rs[kb];
      const f32x4 rb = *(const f32x4*)&Rs[kb + 4];
      const float xacc = v[0] * ra[0] + v[1] * ra[1] + v[2] * ra[2] +
                         v[3] * ra[3] + v[4] * rb[0] + v[5] * rb[1] +
                         v[6] * rb[2] + v[7] * rb[3];
      x[j] = x[j] + (xacc - x[j]) * INV_TAU_X;
    }

    if (t < T) {
      const size_t o = ((size_t)b * T + t);
#pragma unroll
      for (int j = 0; j < 4; ++j) xs[o * K + lane + 64 * j] = x[j];
      z_pred[o * M + lane] = znew;
    }
    z = znew;
  }
}

// ---------------------------------------------------------------------------
// Schedule (5 kernels):
//  ws: X0 = BT*K floats (64 MB) | Wr = split-weight blob (1.1 MB, persistent)
//  1 split8 -> Wr
//  2 F1 fused x-chain: in_seq -> ex1 -> ex2 -> ex3(-> X0 global) -> de1
//       -> de2(-> x_recon)
//  3 F2 fused z-chain: in_seq -> ez1 -> ez2 -> ez3(-> z_seq)
//  4 scan: X0 in-place (x_states) + z_pred
//  5 F3 fused pred-decoder: X0 -> de1 -> de2(-> x_pred)
// ---------------------------------------------------------------------------
extern "C" void kernel_launch(void* const* d_in, const int* in_sizes, int n_in,
                              void* d_out, int out_size, void* d_ws,
                              size_t ws_size, hipStream_t stream) {
  const float* in_seq = (const float*)d_in[0];
  const float* Lm    = (const float*)d_in[1];
  const float* Rm    = (const float*)d_in[2];
  const float* Wz    = (const float*)d_in[3];
  const float* Az_w  = (const float*)d_in[4];
  const float* Az_b  = (const float*)d_in[5];
  const float* ex1_w = (const float*)d_in[6];
  const float* ex1_b = (const float*)d_in[7];
  const float* ex2_w = (const float*)d_in[8];
  const float* ex2_b = (const float*)d_in[9];
  const float* ex3_w = (const float*)d_in[10];
  const float* ex3_b = (const float*)d_in[11];
  const float* ez1_w = (const float*)d_in[12];
  const float* ez1_b = (const float*)d_in[13];
  const float* ez2_w = (const float*)d_in[14];
  const float* ez2_b = (const float*)d_in[15];
  const float* ez3_w = (const float*)d_in[16];
  const float* ez3_b = (const float*)d_in[17];
  const float* de1_w = (const float*)d_in[18];
  const float* de1_b = (const float*)d_in[19];
  const float* de2_w = (const float*)d_in[20];
  const float* de2_b = (const float*)d_in[21];

  float* out = (float*)d_out;
  float* x_pred  = out;                                        // BT*P
  float* x_recon = out + (size_t)BT * P;                       // BT*P
  float* z_pred  = out + (size_t)2 * BT * P;                   // BT*M
  float* z_seq   = out + (size_t)2 * BT * P + (size_t)BT * M;  // BT*M

  float* X0 = (float*)d_ws;                      // BT*K fp32 (64 MB)
  short* Wr = (short*)(X0 + (size_t)BT * K);     // split-weight blob (1.1 MB)

  // weight offsets in Wr (shorts): hi at hoff, lo at hoff + 4*n4
  const unsigned HO_EX1 = 0,      HO_EX2 = 65536,  HO_EX3 = 196608;
  const unsigned HO_DE1 = 327680, HO_DE2 = 458752;
  const unsigned HO_EZ1 = 524288, HO_EZ2 = 540672, HO_EZ3 = 548864;

  // 1: split all 8 weights into Wr
  W8 w8;
  w8.src[0] = ex1_w; w8.hoff[0] = HO_EX1; w8.n4[0] = 8192;
  w8.src[1] = ex2_w; w8.hoff[1] = HO_EX2; w8.n4[1] = 16384;
  w8.src[2] = ex3_w; w8.hoff[2] = HO_EX3; w8.n4[2] = 16384;
  w8.src[3] = de1_w; w8.hoff[3] = HO_DE1; w8.n4[3] = 16384;
  w8.src[4] = de2_w; w8.hoff[4] = HO_DE2; w8.n4[4] = 8192;
  w8.src[5] = ez1_w; w8.hoff[5] = HO_EZ1; w8.n4[5] = 2048;
  w8.src[6] = ez2_w; w8.hoff[6] = HO_EZ2; w8.n4[6] = 1024;
  w8.src[7] = ez3_w; w8.hoff[7] = HO_EZ3; w8.n4[7] = 1024;
  split8_kernel<<<dim3(64, 8), dim3(256), 0, stream>>>(w8, Wr);

  const dim3 fgrid(BT / 128), fblk(512);

  // 2: F1 fused x-chain (5 layers)
  {
    FusedArgs a{};
    a.A0 = in_seq;
    a.Wh[0] = Wr + HO_EX1; a.Wl[0] = Wr + HO_EX1 + 32768; a.bias[0] = ex1_b;
    a.Wh[1] = Wr + HO_EX2; a.Wl[1] = Wr + HO_EX2 + 65536; a.bias[1] = ex2_b;
    a.Wh[2] = Wr + HO_EX3; a.Wl[2] = Wr + HO_EX3 + 65536; a.bias[2] = ex3_b;
    a.Wh[3] = Wr + HO_DE1; a.Wl[3] = Wr + HO_DE1 + 65536; a.bias[3] = de1_b;
    a.Wh[4] = Wr + HO_DE2; a.Wl[4] = Wr + HO_DE2 + 32768; a.bias[4] = de2_b;
    a.gout[2] = X0;        // x_seq for the scan
    a.gout[4] = x_recon;
    fused_mlp<256, 5, 128, 256, 256, 256, 256, 128>
        <<<fgrid, fblk, 0, stream>>>(a);
  }
  // 3: F2 fused z-chain (3 layers)
  {
    FusedArgs a{};
    a.A0 = in_seq;
    a.Wh[0] = Wr + HO_EZ1; a.Wl[0] = Wr + HO_EZ1 + 8192; a.bias[0] = ez1_b;
    a.Wh[1] = Wr + HO_EZ2; a.Wl[1] = Wr + HO_EZ2 + 4096; a.bias[1] = ez2_b;
    a.Wh[2] = Wr + HO_EZ3; a.Wl[2] = Wr + HO_EZ3 + 4096; a.bias[2] = ez3_b;
    a.gout[2] = z_seq;
    fused_mlp<128, 3, 128, 64, 64, 64, 0, 0><<<fgrid, fblk, 0, stream>>>(a);
  }
  // 4: scan (in-place on X0), z_pred out
  scan_kernel<<<dim3(B * NSEG / 8), dim3(512), 0, stream>>>(
      X0, z_seq, Lm, Rm, Wz, Az_w, Az_b, z_pred);
  // 5: F3 fused pred-decoder (2 layers)
  {
    FusedArgs a{};
    a.A0 = X0;
    a.Wh[0] = Wr + HO_DE1; a.Wl[0] = Wr + HO_DE1 + 65536; a.bias[0] = de1_b;
    a.Wh[1] = Wr + HO_DE2; a.Wl[1] = Wr + HO_DE2 + 32768; a.bias[1] = de2_b;
    a.gout[1] = x_pred;
    fused_mlp<256, 2, 256, 256, 128, 0, 0, 0><<<fgrid, fblk, 0, stream>>>(a);
  }
}

// Round 9
// 624.324 us; speedup vs baseline: 1.1084x; 1.1084x over previous
//
#include <hip/hip_runtime.h>
#include <math.h>

// Problem constants
constexpr int B = 32, T = 2048, P = 128, K = 256, R = 8, M = 64;
constexpr int BT = B * T;                 // 65536 rows
constexpr int TAU = 5;
constexpr int NSEG = (T + TAU - 1) / TAU; // 410 segments
constexpr float INV_TAU_X = 1.0f / 100.0f;
constexpr float INV_TAU_Z = 1.0f / 100.0f;

typedef short bf16x4 __attribute__((ext_vector_type(4)));
typedef short bf16x8 __attribute__((ext_vector_type(8)));
typedef float f32x4 __attribute__((ext_vector_type(4)));

// fp32 <-> bf16 (RNE)
static __device__ __forceinline__ short f2bf(float f) {
  unsigned u = __builtin_bit_cast(unsigned, f);
  u += 0x7FFF + ((u >> 16) & 1);
  return (short)(u >> 16);
}
static __device__ __forceinline__ float bf2f(short h) {
  unsigned u = ((unsigned)(unsigned short)h) << 16;
  return __builtin_bit_cast(float, u);
}

// fast transcendentals (v_exp + v_rcp, ~1e-6 rel — invisible vs 2e-2 thresh)
static __device__ __forceinline__ float tanh_fast(float x) {
  const float e = __expf(2.f * x);
  return 1.f - 2.f * __builtin_amdgcn_rcpf(e + 1.f);
}
static __device__ __forceinline__ float sigmoid_fast(float x) {
  return __builtin_amdgcn_rcpf(1.f + __expf(-x));
}

// ---------------------------------------------------------------------------
// 64-lane all-reduce (sum) for 8 values. Stages 1-4 are the rocPRIM-standard
// gfx9 DPP ladder (all-VALU); stage 5 = ds_swizzle 0x401F (xor16), stage 6 =
// __shfl_xor 32. NOTE: gfx950 permlane16/32_swap builtins produced wrong
// sums here (r1 fail) — semantics differ from the assumed two-reg swap.
// ---------------------------------------------------------------------------
template <int CTRL>
static __device__ __forceinline__ float dppadd(float p) {
  return p + __builtin_bit_cast(
                 float, __builtin_amdgcn_update_dpp(
                            0, __builtin_bit_cast(int, p), CTRL, 0xF, 0xF, true));
}

static __device__ __forceinline__ void allreduce8(float p[R]) {
#pragma unroll
  for (int r = 0; r < R; ++r) p[r] = dppadd<0xB1>(p[r]);   // quad_perm [1,0,3,2]
#pragma unroll
  for (int r = 0; r < R; ++r) p[r] = dppadd<0x4E>(p[r]);   // quad_perm [2,3,0,1]
#pragma unroll
  for (int r = 0; r < R; ++r) p[r] = dppadd<0x141>(p[r]);  // row_half_mirror
#pragma unroll
  for (int r = 0; r < R; ++r) p[r] = dppadd<0x140>(p[r]);  // row_mirror
#pragma unroll
  for (int r = 0; r < R; ++r)                              // xor 16 (in-half)
    p[r] += __builtin_bit_cast(float, __builtin_amdgcn_ds_swizzle(
                                          __builtin_bit_cast(int, p[r]), 0x401F));
#pragma unroll
  for (int r = 0; r < R; ++r)                              // xor 32 (cross-half)
    p[r] += __shfl_xor(p[r], 32, 64);
}

// Batched split of the 8 weight matrices into one region: weight w's hi at
// dst+hoff[w], lo at dst+hoff[w]+4*n4[w].
struct W8 {
  const float* src[8];
  unsigned hoff[8];  // in shorts
  unsigned n4[8];
};
__global__ __launch_bounds__(256) void split8_kernel(W8 p, short* __restrict__ dst) {
  const int w = blockIdx.y;
  const int i = blockIdx.x * 256 + threadIdx.x;
  if (i >= (int)p.n4[w]) return;
  const float4 v = ((const float4*)p.src[w])[i];
  const float f[4] = {v.x, v.y, v.z, v.w};
  bf16x4 ph, pl;
#pragma unroll
  for (int q = 0; q < 4; ++q) {
    ph[q] = f2bf(f[q]);
    pl[q] = f2bf(f[q] - bf2f(ph[q]));
  }
  *(bf16x4*)&dst[p.hoff[w] + i * 4] = ph;
  *(bf16x4*)&dst[p.hoff[w] + p.n4[w] * 4 + i * 4] = pl;
}

// ---------------------------------------------------------------------------
// r9: fused MLP chain, geometry fixed per r8 counters.
//  r8 post-mortem: FETCH dropped as designed (fusion works) but F1=367us,
//  MfmaUtil 11%, 4.7M LDS bank conflicts, 1 block/CU. Two bugs:
//  (a) buf[row][KIN] row stride = 256 floats = 8 bank sweeps -> the swizzle
//      only spanned 4 of 8 16B-slots over a wave's A read = 16 dwords/bank
//      (2x the 8/bank b128 floor).
//  (b) 128 KiB LDS -> 2 waves/SIMD; L2 B-load latency fully exposed.
//  Fix:
//  - Per-k-tile LDS layout [kt][64][32] fp32: row-tile = 32 floats = 128 B
//    = ONE bank sweep with 8 16B slots; swizzle slot = chunk ^ (row&7)
//    (r2/r6-proven balanced scheme: exactly 8 dwords/bank per b128 read).
//    Applied identically at staging, A-frag reads, epilogue writes.
//  - 64-row strips: LDS = 64*MAXW*4 <= 64 KB -> 2 blocks/CU (4 waves/SIMD),
//    grid 1024, __launch_bounds__(512,4) (VGPR<=128; acc is only 32 now).
//  - Per-kt B loads hoisted ahead of the MFMA cluster (independent issue).
//  Wave grid 2M x 4N: wave owns rows wm*32+i*16+l16 (i=0,1) and the cg
//  quarter of output cols. Math order (k0 ascending, in-reg h/l split,
//  hh/lh/hl) is bit-identical to r5/r6/r8 -> same absmax.
//  All barriers wave-uniform (constexpr structure, uniform `if (gout)`).
// ---------------------------------------------------------------------------
struct FusedArgs {
  const float* A0;       // global input, width K0, BT rows
  const short* Wh[5];    // split weights (hi)
  const short* Wl[5];    // split weights (lo)
  const float* bias[5];
  float* gout[5];        // optional global output per layer (nullptr = none)
};

template <int I> struct Ly { static constexpr int v = I; };

template <int MAXW, int NL, int K0, int K1, int K2, int K3, int K4, int K5>
__global__ __launch_bounds__(512, 4) void fused_mlp(FusedArgs p) {
  constexpr int Kd[6] = {K0, K1, K2, K3, K4, K5};
  __shared__ float buf[64 * MAXW];  // tiled: [W/32][64][32]

  const int tid = threadIdx.x;
  const int wave = tid >> 6, lane = tid & 63;
  const int l16 = lane & 15, quad = lane >> 4;
  const int wm = wave >> 2, cg = wave & 3;
  const int row0 = blockIdx.x * 64;

  // stage layer-0 input rows into tiled-swizzled LDS
  constexpr int G0 = K0 / 8;  // 8-float groups per row
  for (int c = tid; c < 64 * G0; c += 512) {
    const int row = c / G0, g = c % G0;
    const float* gp = p.A0 + (size_t)(row0 + row) * K0 + g * 8;
    const f32x4 v0 = *(const f32x4*)gp;
    const f32x4 v1 = *(const f32x4*)(gp + 4);
    const int kt = g >> 2, cp = (g & 3) * 2;  // chunk pair cp, cp+1
    float* tb = &buf[(kt * 64 + row) * 32];
    *(f32x4*)&tb[((cp) ^ (row & 7)) * 4] = v0;
    *(f32x4*)&tb[((cp + 1) ^ (row & 7)) * 4] = v1;
  }
  __syncthreads();

  auto do_layer = [&](auto lc) {
    constexpr int l = decltype(lc)::v;
    constexpr int KIN = Kd[l], KOUT = Kd[l + 1];
    constexpr int JT = KOUT / 64;   // 16-col tiles per wave (quarter cols)
    constexpr int NKT = KIN / 32;   // k tiles
    const int cols0w = cg * (KOUT / 4);

    f32x4 acc[2][JT];
#pragma unroll
    for (int i = 0; i < 2; ++i)
#pragma unroll
      for (int j = 0; j < JT; ++j) acc[i][j] = (f32x4){0.f, 0.f, 0.f, 0.f};

#pragma unroll
    for (int kt = 0; kt < NKT; ++kt) {
      // B frags for this k-tile (L2-resident), all issued up front
      bf16x8 bh[JT], bl[JT];
#pragma unroll
      for (int j = 0; j < JT; ++j) {
        const size_t boff =
            (size_t)(cols0w + j * 16 + l16) * KIN + kt * 32 + quad * 8;
        bh[j] = *(const bf16x8*)(p.Wh[l] + boff);
        bl[j] = *(const bf16x8*)(p.Wl[l] + boff);
      }
      // A frags from LDS (balanced swizzle: s0=(2q)^(row&7), s1=s0^1)
      bf16x8 ah[2], al[2];
#pragma unroll
      for (int i = 0; i < 2; ++i) {
        const int rowr = wm * 32 + i * 16 + l16;
        const float* tb = &buf[(kt * 64 + rowr) * 32];
        const int s0 = (2 * quad) ^ (rowr & 7);
        const f32x4 a0 = *(const f32x4*)&tb[s0 * 4];
        const f32x4 a1 = *(const f32x4*)&tb[(s0 ^ 1) * 4];
#pragma unroll
        for (int e = 0; e < 4; ++e) {
          ah[i][e] = f2bf(a0[e]);
          al[i][e] = f2bf(a0[e] - bf2f(ah[i][e]));
          ah[i][4 + e] = f2bf(a1[e]);
          al[i][4 + e] = f2bf(a1[e] - bf2f(ah[i][4 + e]));
        }
      }
#pragma unroll
      for (int j = 0; j < JT; ++j)
#pragma unroll
        for (int i = 0; i < 2; ++i) {
          acc[i][j] = __builtin_amdgcn_mfma_f32_16x16x32_bf16(ah[i], bh[j],
                                                              acc[i][j], 0, 0, 0);
          acc[i][j] = __builtin_amdgcn_mfma_f32_16x16x32_bf16(al[i], bh[j],
                                                              acc[i][j], 0, 0, 0);
          acc[i][j] = __builtin_amdgcn_mfma_f32_16x16x32_bf16(ah[i], bl[j],
                                                              acc[i][j], 0, 0, 0);
        }
    }
    if constexpr (l < NL - 1) __syncthreads();  // all A reads done

    // epilogue: tanh -> LDS (next A, tiled-swizzled) and/or global
    float* gout = p.gout[l];
#pragma unroll
    for (int j = 0; j < JT; ++j) {
      const int col = cols0w + j * 16 + l16;
      const float bj = p.bias[l][col];
#pragma unroll
      for (int i = 0; i < 2; ++i) {
#pragma unroll
        for (int r = 0; r < 4; ++r) {
          const float v = tanh_fast(acc[i][j][r] + bj);
          const int row = wm * 32 + i * 16 + quad * 4 + r;
          if constexpr (l < NL - 1) {
            const int kt = col >> 5, cc = (col & 31) >> 2, e = col & 3;
            buf[(kt * 64 + row) * 32 + ((cc ^ (row & 7)) << 2) + e] = v;
          }
          if (gout) gout[(size_t)(row0 + row) * KOUT + col] = v;
        }
      }
    }
    if constexpr (l < NL - 1) __syncthreads();  // next A ready
  };

  do_layer(Ly<0>{});
  if constexpr (NL > 1) do_layer(Ly<1>{});
  if constexpr (NL > 2) do_layer(Ly<2>{});
  if constexpr (NL > 3) do_layer(Ly<3>{});
  if constexpr (NL > 4) do_layer(Ly<4>{});
}

// ---------------------------------------------------------------------------
// Scan: unchanged from r6 (proven, ~78 µs). Reset every TAU=5 -> independent
// (batch, segment) chains; one wave per chain, 8 waves/block, no inner
// barriers. fp32 x in-place on X0.
// ---------------------------------------------------------------------------
__global__ __launch_bounds__(512) void scan_kernel(
    float* xs,                                 // fp32 x_seq / x_states (in-place)
    const float* __restrict__ z_seq,           // fp32
    const float* __restrict__ Lm, const float* __restrict__ Rm,
    const float* __restrict__ Wz, const float* __restrict__ Az_w,
    const float* __restrict__ Az_b,
    float* __restrict__ z_pred) {
  __shared__ __align__(16) float Wz_s[M][68];  // stride 68: 16B rows, balanced
  __shared__ __align__(16) float Ls[K * R];    // native [k][r] layout
  __shared__ __align__(16) float Rs[K * R];    // native [k][r] layout
  __shared__ __align__(16) float tz_s[8][M];   // per-wave rows (256 B aligned)

  const int tid = threadIdx.x;
  for (int i = tid; i < M * M; i += 512) Wz_s[i >> 6][i & 63] = Wz[i];
  // K*R = 2048 floats = 512 float4 -> exactly one per thread
  ((float4*)Ls)[tid] = ((const float4*)Lm)[tid];
  ((float4*)Rs)[tid] = ((const float4*)Rm)[tid];
  __syncthreads();

  const int wave = tid >> 6;
  const int lane = tid & 63;
  const int chain = blockIdx.x * 8 + wave;
  const int b = chain / NSEG;
  const int seg = chain % NSEG;
  const int t0 = seg * TAU;

  // per-lane register caches (reused all 5 steps)
  float azw[R], azb[R];
#pragma unroll
  for (int r = 0; r < R; ++r) {
    azw[r] = Az_w[r * M + lane];
    azb[r] = Az_b[r];
  }

  float x[4], z;
  {
    const size_t base = ((size_t)b * T + t0);
#pragma unroll
    for (int j = 0; j < 4; ++j) x[j] = xs[base * K + lane + 64 * j];
    z = z_seq[base * M + lane];
  }

  const float4* wrow = (const float4*)&Wz_s[lane][0];  // lane*272 B, 16-al.
  const float4* trow = (const float4*)&tz_s[wave][0];

  for (int tt = 0; tt < TAU; ++tt) {
    const int t = t0 + tt;
    // z update: z += (tanh(z) @ Wz^T - z)/100
    const float tz = tanh_fast(z);
    tz_s[wave][lane] = tz;  // wave-private row; intra-wave DS order suffices
    float zacc = 0.f;
#pragma unroll
    for (int j = 0; j < 16; ++j) {
      const float4 w = wrow[j], tv = trow[j];
      zacc += w.x * tv.x + w.y * tv.y + w.z * tv.z + w.w * tv.w;
    }
    const float znew = z + (zacc - z) * INV_TAU_Z;

    // s = sigmoid(z_new @ Az^T + b)  — DPP/swizzle butterfly reduce
    float s[R];
#pragma unroll
    for (int r = 0; r < R; ++r) s[r] = znew * azw[r];
    allreduce8(s);
#pragma unroll
    for (int r = 0; r < R; ++r) s[r] = sigmoid_fast(s[r] + azb[r]);

    // x update: u = tanh(x) @ L ; v = u*s ; x += (v @ Rm^T - x)/100
    float tx4[4];
#pragma unroll
    for (int j = 0; j < 4; ++j) tx4[j] = tanh_fast(x[j]);
    float v[R];
#pragma unroll
    for (int r = 0; r < R; ++r) v[r] = 0.f;
#pragma unroll
    for (int j = 0; j < 4; ++j) {
      const int kb = (lane + 64 * j) * 8;
      const f32x4 la = *(const f32x4*)&Ls[kb];
      const f32x4 lb = *(const f32x4*)&Ls[kb + 4];
      const float txj = tx4[j];
      v[0] += txj * la[0]; v[1] += txj * la[1];
      v[2] += txj * la[2]; v[3] += txj * la[3];
      v[4] += txj * lb[0]; v[5] += txj * lb[1];
      v[6] += txj * lb[2]; v[7] += txj * lb[3];
    }
    allreduce8(v);
#pragma unroll
    for (int r = 0; r < R; ++r) v[r] *= s[r];
#pragma unroll
    for (int j = 0; j < 4; ++j) {
      const int kb = (lane + 64 * j) * 8;
      const f32x4 ra = *(const f32x4*)&Rs[kb];
      const f32x4 rb = *(const f32x4*)&Rs[kb + 4];
      const float xacc = v[0] * ra[0] + v[1] * ra[1] + v[2] * ra[2] +
                         v[3] * ra[3] + v[4] * rb[0] + v[5] * rb[1] +
                         v[6] * rb[2] + v[7] * rb[3];
      x[j] = x[j] + (xacc - x[j]) * INV_TAU_X;
    }

    if (t < T) {
      const size_t o = ((size_t)b * T + t);
#pragma unroll
      for (int j = 0; j < 4; ++j) xs[o * K + lane + 64 * j] = x[j];
      z_pred[o * M + lane] = znew;
    }
    z = znew;
  }
}

// ---------------------------------------------------------------------------
// Schedule (5 kernels):
//  ws: X0 = BT*K floats (64 MB) | Wr = split-weight blob (1.1 MB, persistent)
//  1 split8 -> Wr
//  2 F1 fused x-chain: in_seq -> ex1 -> ex2 -> ex3(-> X0 global) -> de1
//       -> de2(-> x_recon)
//  3 F2 fused z-chain: in_seq -> ez1 -> ez2 -> ez3(-> z_seq)
//  4 scan: X0 in-place (x_states) + z_pred
//  5 F3 fused pred-decoder: X0 -> de1 -> de2(-> x_pred)
// ---------------------------------------------------------------------------
extern "C" void kernel_launch(void* const* d_in, const int* in_sizes, int n_in,
                              void* d_out, int out_size, void* d_ws,
                              size_t ws_size, hipStream_t stream) {
  const float* in_seq = (const float*)d_in[0];
  const float* Lm    = (const float*)d_in[1];
  const float* Rm    = (const float*)d_in[2];
  const float* Wz    = (const float*)d_in[3];
  const float* Az_w  = (const float*)d_in[4];
  const float* Az_b  = (const float*)d_in[5];
  const float* ex1_w = (const float*)d_in[6];
  const float* ex1_b = (const float*)d_in[7];
  const float* ex2_w = (const float*)d_in[8];
  const float* ex2_b = (const float*)d_in[9];
  const float* ex3_w = (const float*)d_in[10];
  const float* ex3_b = (const float*)d_in[11];
  const float* ez1_w = (const float*)d_in[12];
  const float* ez1_b = (const float*)d_in[13];
  const float* ez2_w = (const float*)d_in[14];
  const float* ez2_b = (const float*)d_in[15];
  const float* ez3_w = (const float*)d_in[16];
  const float* ez3_b = (const float*)d_in[17];
  const float* de1_w = (const float*)d_in[18];
  const float* de1_b = (const float*)d_in[19];
  const float* de2_w = (const float*)d_in[20];
  const float* de2_b = (const float*)d_in[21];

  float* out = (float*)d_out;
  float* x_pred  = out;                                        // BT*P
  float* x_recon = out + (size_t)BT * P;                       // BT*P
  float* z_pred  = out + (size_t)2 * BT * P;                   // BT*M
  float* z_seq   = out + (size_t)2 * BT * P + (size_t)BT * M;  // BT*M

  float* X0 = (float*)d_ws;                      // BT*K fp32 (64 MB)
  short* Wr = (short*)(X0 + (size_t)BT * K);     // split-weight blob (1.1 MB)

  // weight offsets in Wr (shorts): hi at hoff, lo at hoff + 4*n4
  const unsigned HO_EX1 = 0,      HO_EX2 = 65536,  HO_EX3 = 196608;
  const unsigned HO_DE1 = 327680, HO_DE2 = 458752;
  const unsigned HO_EZ1 = 524288, HO_EZ2 = 540672, HO_EZ3 = 548864;

  // 1: split all 8 weights into Wr
  W8 w8;
  w8.src[0] = ex1_w; w8.hoff[0] = HO_EX1; w8.n4[0] = 8192;
  w8.src[1] = ex2_w; w8.hoff[1] = HO_EX2; w8.n4[1] = 16384;
  w8.src[2] = ex3_w; w8.hoff[2] = HO_EX3; w8.n4[2] = 16384;
  w8.src[3] = de1_w; w8.hoff[3] = HO_DE1; w8.n4[3] = 16384;
  w8.src[4] = de2_w; w8.hoff[4] = HO_DE2; w8.n4[4] = 8192;
  w8.src[5] = ez1_w; w8.hoff[5] = HO_EZ1; w8.n4[5] = 2048;
  w8.src[6] = ez2_w; w8.hoff[6] = HO_EZ2; w8.n4[6] = 1024;
  w8.src[7] = ez3_w; w8.hoff[7] = HO_EZ3; w8.n4[7] = 1024;
  split8_kernel<<<dim3(64, 8), dim3(256), 0, stream>>>(w8, Wr);

  const dim3 fgrid(BT / 64), fblk(512);

  // 2: F1 fused x-chain (5 layers)
  {
    FusedArgs a{};
    a.A0 = in_seq;
    a.Wh[0] = Wr + HO_EX1; a.Wl[0] = Wr + HO_EX1 + 32768; a.bias[0] = ex1_b;
    a.Wh[1] = Wr + HO_EX2; a.Wl[1] = Wr + HO_EX2 + 65536; a.bias[1] = ex2_b;
    a.Wh[2] = Wr + HO_EX3; a.Wl[2] = Wr + HO_EX3 + 65536; a.bias[2] = ex3_b;
    a.Wh[3] = Wr + HO_DE1; a.Wl[3] = Wr + HO_DE1 + 65536; a.bias[3] = de1_b;
    a.Wh[4] = Wr + HO_DE2; a.Wl[4] = Wr + HO_DE2 + 32768; a.bias[4] = de2_b;
    a.gout[2] = X0;        // x_seq for the scan
    a.gout[4] = x_recon;
    fused_mlp<256, 5, 128, 256, 256, 256, 256, 128>
        <<<fgrid, fblk, 0, stream>>>(a);
  }
  // 3: F2 fused z-chain (3 layers)
  {
    FusedArgs a{};
    a.A0 = in_seq;
    a.Wh[0] = Wr + HO_EZ1; a.Wl[0] = Wr + HO_EZ1 + 8192; a.bias[0] = ez1_b;
    a.Wh[1] = Wr + HO_EZ2; a.Wl[1] = Wr + HO_EZ2 + 4096; a.bias[1] = ez2_b;
    a.Wh[2] = Wr + HO_EZ3; a.Wl[2] = Wr + HO_EZ3 + 4096; a.bias[2] = ez3_b;
    a.gout[2] = z_seq;
    fused_mlp<128, 3, 128, 64, 64, 64, 0, 0><<<fgrid, fblk, 0, stream>>>(a);
  }
  // 4: scan (in-place on X0), z_pred out
  scan_kernel<<<dim3(B * NSEG / 8), dim3(512), 0, stream>>>(
      X0, z_seq, Lm, Rm, Wz, Az_w, Az_b, z_pred);
  // 5: F3 fused pred-decoder (2 layers)
  {
    FusedArgs a{};
    a.A0 = X0;
    a.Wh[0] = Wr + HO_DE1; a.Wl[0] = Wr + HO_DE1 + 65536; a.bias[0] = de1_b;
    a.Wh[1] = Wr + HO_DE2; a.Wl[1] = Wr + HO_DE2 + 32768; a.bias[1] = de2_b;
    a.gout[1] = x_pred;
    fused_mlp<256, 2, 256, 256, 128, 0, 0, 0><<<fgrid, fblk, 0, stream>>>(a);
  }
}

// Round 10
// 618.819 us; speedup vs baseline: 1.1182x; 1.0089x over previous
//
#include <hip/hip_runtime.h>
#include <math.h>

// Problem constants
constexpr int B = 32, T = 2048, P = 128, K = 256, R = 8, M = 64;
constexpr int BT = B * T;                 // 65536 rows
constexpr int TAU = 5;
constexpr int NSEG = (T + TAU - 1) / TAU; // 410 segments
constexpr float INV_TAU_X = 1.0f / 100.0f;
constexpr float INV_TAU_Z = 1.0f / 100.0f;

typedef short bf16x4 __attribute__((ext_vector_type(4)));
typedef short bf16x8 __attribute__((ext_vector_type(8)));
typedef float f32x4 __attribute__((ext_vector_type(4)));

// fp32 <-> bf16 (RNE)
static __device__ __forceinline__ short f2bf(float f) {
  unsigned u = __builtin_bit_cast(unsigned, f);
  u += 0x7FFF + ((u >> 16) & 1);
  return (short)(u >> 16);
}
static __device__ __forceinline__ float bf2f(short h) {
  unsigned u = ((unsigned)(unsigned short)h) << 16;
  return __builtin_bit_cast(float, u);
}

// fast transcendentals (v_exp + v_rcp, ~1e-6 rel — invisible vs 2e-2 thresh)
static __device__ __forceinline__ float tanh_fast(float x) {
  const float e = __expf(2.f * x);
  return 1.f - 2.f * __builtin_amdgcn_rcpf(e + 1.f);
}
static __device__ __forceinline__ float sigmoid_fast(float x) {
  return __builtin_amdgcn_rcpf(1.f + __expf(-x));
}

// ---------------------------------------------------------------------------
// 64-lane all-reduce (sum) for 8 values. Stages 1-4 are the rocPRIM-standard
// gfx9 DPP ladder (all-VALU); stage 5 = ds_swizzle 0x401F (xor16), stage 6 =
// __shfl_xor 32. NOTE: gfx950 permlane16/32_swap builtins produced wrong
// sums here (r1 fail) — semantics differ from the assumed two-reg swap.
// ---------------------------------------------------------------------------
template <int CTRL>
static __device__ __forceinline__ float dppadd(float p) {
  return p + __builtin_bit_cast(
                 float, __builtin_amdgcn_update_dpp(
                            0, __builtin_bit_cast(int, p), CTRL, 0xF, 0xF, true));
}

static __device__ __forceinline__ void allreduce8(float p[R]) {
#pragma unroll
  for (int r = 0; r < R; ++r) p[r] = dppadd<0xB1>(p[r]);   // quad_perm [1,0,3,2]
#pragma unroll
  for (int r = 0; r < R; ++r) p[r] = dppadd<0x4E>(p[r]);   // quad_perm [2,3,0,1]
#pragma unroll
  for (int r = 0; r < R; ++r) p[r] = dppadd<0x141>(p[r]);  // row_half_mirror
#pragma unroll
  for (int r = 0; r < R; ++r) p[r] = dppadd<0x140>(p[r]);  // row_mirror
#pragma unroll
  for (int r = 0; r < R; ++r)                              // xor 16 (in-half)
    p[r] += __builtin_bit_cast(float, __builtin_amdgcn_ds_swizzle(
                                          __builtin_bit_cast(int, p[r]), 0x401F));
#pragma unroll
  for (int r = 0; r < R; ++r)                              // xor 32 (cross-half)
    p[r] += __shfl_xor(p[r], 32, 64);
}

// Batched split of the 8 weight matrices into one region: weight w's hi at
// dst+hoff[w], lo at dst+hoff[w]+4*n4[w].
struct W8 {
  const float* src[8];
  unsigned hoff[8];  // in shorts
  unsigned n4[8];
};
__global__ __launch_bounds__(256) void split8_kernel(W8 p, short* __restrict__ dst) {
  const int w = blockIdx.y;
  const int i = blockIdx.x * 256 + threadIdx.x;
  if (i >= (int)p.n4[w]) return;
  const float4 v = ((const float4*)p.src[w])[i];
  const float f[4] = {v.x, v.y, v.z, v.w};
  bf16x4 ph, pl;
#pragma unroll
  for (int q = 0; q < 4; ++q) {
    ph[q] = f2bf(f[q]);
    pl[q] = f2bf(f[q] - bf2f(ph[q]));
  }
  *(bf16x4*)&dst[p.hoff[w] + i * 4] = ph;
  *(bf16x4*)&dst[p.hoff[w] + p.n4[w] * 4 + i * 4] = pl;
}

// ---------------------------------------------------------------------------
// r10: fused MLP chain with PRE-SPLIT bf16 LDS activations.
//  r9 post-mortem: A-reads were already bank-balanced (conflict counter =
//  4.2 cyc/b128 = the balanced-read floor signature; r8's 8.0 was real).
//  Real bottleneck: VALUBusy 27% vs MfmaUtil 13% — the fp32->h/l split ran
//  at CONSUMPTION (6 VALU/elem, x4 redundant across the 4 col-group waves
//  reading each row) and sat on the ds_read->split->MFMA critical path.
//  Fix: LDS holds bf16 h and l PLANES (r2's proven operand format):
//   - stage-in splits in_seq once; each epilogue splits its output once at
//     production. k-loop A path is now ds_read_b128 -> MFMA direct.
//   - layout [kt64][64][64] shorts/plane: row-tile = 64 shorts = 128 B =
//     one bank sweep, 8x16B chunks, slot = chunk^(row&7) (r2-proven,
//     8 dwords/bank floor) at stage-in, A-reads, epilogue writes alike.
//   - same 64 KB LDS total -> 2 blocks/CU; VGPR ~100 leaves room for the
//     compiler to pipeline the L2-resident B loads across the unrolled
//     k-loop.
//  Split-at-production == split-at-consumption of the same fp32 value, and
//  k-order/MFMA order (hh,lh,hl; k ascending) unchanged -> bit-identical
//  results to r5/r6/r8/r9 (absmax 0.00390625).
//  Wave grid 2M x 4N; all barriers wave-uniform.
// ---------------------------------------------------------------------------
struct FusedArgs {
  const float* A0;       // global input, width K0, BT rows
  const short* Wh[5];    // split weights (hi)
  const short* Wl[5];    // split weights (lo)
  const float* bias[5];
  float* gout[5];        // optional global output per layer (nullptr = none)
};

template <int I> struct Ly { static constexpr int v = I; };

template <int MAXW, int NL, int K0, int K1, int K2, int K3, int K4, int K5>
__global__ __launch_bounds__(512, 4) void fused_mlp(FusedArgs p) {
  constexpr int Kd[6] = {K0, K1, K2, K3, K4, K5};
  __shared__ short bufh[64 * MAXW];  // [W/64][64][64] shorts, swizzled
  __shared__ short bufl[64 * MAXW];

  const int tid = threadIdx.x;
  const int wave = tid >> 6, lane = tid & 63;
  const int l16 = lane & 15, quad = lane >> 4;
  const int wm = wave >> 2, cg = wave & 3;
  const int row0 = blockIdx.x * 64;

  // stage layer-0: global fp32 -> split bf16 h/l planes (8 floats/unit)
  constexpr int G0 = K0 / 8;
  for (int u = tid; u < 64 * G0; u += 512) {
    const int row = u / G0, g = u % G0;
    const float* gp = p.A0 + (size_t)(row0 + row) * K0 + g * 8;
    const f32x4 v0 = *(const f32x4*)gp;
    const f32x4 v1 = *(const f32x4*)(gp + 4);
    bf16x8 ph, pl;
#pragma unroll
    for (int e = 0; e < 4; ++e) {
      ph[e] = f2bf(v0[e]);
      pl[e] = f2bf(v0[e] - bf2f(ph[e]));
      ph[4 + e] = f2bf(v1[e]);
      pl[4 + e] = f2bf(v1[e] - bf2f(ph[4 + e]));
    }
    const int off = ((g >> 3) * 64 + row) * 64 + (((g & 7) ^ (row & 7)) * 8);
    *(bf16x8*)&bufh[off] = ph;
    *(bf16x8*)&bufl[off] = pl;
  }
  __syncthreads();

  auto do_layer = [&](auto lc) {
    constexpr int l = decltype(lc)::v;
    constexpr int KIN = Kd[l], KOUT = Kd[l + 1];
    constexpr int JT = KOUT / 64;   // 16-col tiles per wave (quarter cols)
    constexpr int NT64 = KIN / 64;  // 64-k LDS tiles
    const int cols0w = cg * (KOUT / 4);

    f32x4 acc[2][JT];
#pragma unroll
    for (int i = 0; i < 2; ++i)
#pragma unroll
      for (int j = 0; j < JT; ++j) acc[i][j] = (f32x4){0.f, 0.f, 0.f, 0.f};

#pragma unroll
    for (int kt = 0; kt < NT64; ++kt) {
#pragma unroll
      for (int kk = 0; kk < 2; ++kk) {
        const int qc = kk * 4 + quad;
        // B frags (L2-resident blob), issued ahead of the MFMA cluster
        bf16x8 bh[JT], bl[JT];
#pragma unroll
        for (int j = 0; j < JT; ++j) {
          const size_t boff = (size_t)(cols0w + j * 16 + l16) * KIN +
                              kt * 64 + kk * 32 + quad * 8;
          bh[j] = *(const bf16x8*)(p.Wh[l] + boff);
          bl[j] = *(const bf16x8*)(p.Wl[l] + boff);
        }
        // A frags straight from split LDS (no VALU on the path)
        bf16x8 ah[2], al[2];
#pragma unroll
        for (int i = 0; i < 2; ++i) {
          const int r = wm * 32 + i * 16 + l16;
          const int off = (kt * 64 + r) * 64 + ((qc ^ (r & 7)) * 8);
          ah[i] = *(const bf16x8*)&bufh[off];
          al[i] = *(const bf16x8*)&bufl[off];
        }
#pragma unroll
        for (int j = 0; j < JT; ++j)
#pragma unroll
          for (int i = 0; i < 2; ++i) {
            acc[i][j] = __builtin_amdgcn_mfma_f32_16x16x32_bf16(
                ah[i], bh[j], acc[i][j], 0, 0, 0);
            acc[i][j] = __builtin_amdgcn_mfma_f32_16x16x32_bf16(
                al[i], bh[j], acc[i][j], 0, 0, 0);
            acc[i][j] = __builtin_amdgcn_mfma_f32_16x16x32_bf16(
                ah[i], bl[j], acc[i][j], 0, 0, 0);
          }
      }
    }
    if constexpr (l < NL - 1) __syncthreads();  // all A reads done

    // epilogue: tanh; split ONCE at production -> LDS planes and/or global
    float* gout = p.gout[l];
#pragma unroll
    for (int j = 0; j < JT; ++j) {
      const int col = cols0w + j * 16 + l16;
      const float bj = p.bias[l][col];
#pragma unroll
      for (int i = 0; i < 2; ++i) {
#pragma unroll
        for (int r = 0; r < 4; ++r) {
          const float v = tanh_fast(acc[i][j][r] + bj);
          const int row = wm * 32 + i * 16 + quad * 4 + r;
          if constexpr (l < NL - 1) {
            const int off = ((col >> 6) * 64 + row) * 64 +
                            ((((col & 63) >> 3) ^ (row & 7)) * 8) + (col & 7);
            const short h = f2bf(v);
            bufh[off] = h;
            bufl[off] = f2bf(v - bf2f(h));
          }
          if (gout) gout[(size_t)(row0 + row) * KOUT + col] = v;
        }
      }
    }
    if constexpr (l < NL - 1) __syncthreads();  // next A ready
  };

  do_layer(Ly<0>{});
  if constexpr (NL > 1) do_layer(Ly<1>{});
  if constexpr (NL > 2) do_layer(Ly<2>{});
  if constexpr (NL > 3) do_layer(Ly<3>{});
  if constexpr (NL > 4) do_layer(Ly<4>{});
}

// ---------------------------------------------------------------------------
// Scan: unchanged from r6 (proven, ~78 µs). Reset every TAU=5 -> independent
// (batch, segment) chains; one wave per chain, 8 waves/block, no inner
// barriers. fp32 x in-place on X0.
// ---------------------------------------------------------------------------
__global__ __launch_bounds__(512) void scan_kernel(
    float* xs,                                 // fp32 x_seq / x_states (in-place)
    const float* __restrict__ z_seq,           // fp32
    const float* __restrict__ Lm, const float* __restrict__ Rm,
    const float* __restrict__ Wz, const float* __restrict__ Az_w,
    const float* __restrict__ Az_b,
    float* __restrict__ z_pred) {
  __shared__ __align__(16) float Wz_s[M][68];  // stride 68: 16B rows, balanced
  __shared__ __align__(16) float Ls[K * R];    // native [k][r] layout
  __shared__ __align__(16) float Rs[K * R];    // native [k][r] layout
  __shared__ __align__(16) float tz_s[8][M];   // per-wave rows (256 B aligned)

  const int tid = threadIdx.x;
  for (int i = tid; i < M * M; i += 512) Wz_s[i >> 6][i & 63] = Wz[i];
  // K*R = 2048 floats = 512 float4 -> exactly one per thread
  ((float4*)Ls)[tid] = ((const float4*)Lm)[tid];
  ((float4*)Rs)[tid] = ((const float4*)Rm)[tid];
  __syncthreads();

  const int wave = tid >> 6;
  const int lane = tid & 63;
  const int chain = blockIdx.x * 8 + wave;
  const int b = chain / NSEG;
  const int seg = chain % NSEG;
  const int t0 = seg * TAU;

  // per-lane register caches (reused all 5 steps)
  float azw[R], azb[R];
#pragma unroll
  for (int r = 0; r < R; ++r) {
    azw[r] = Az_w[r * M + lane];
    azb[r] = Az_b[r];
  }

  float x[4], z;
  {
    const size_t base = ((size_t)b * T + t0);
#pragma unroll
    for (int j = 0; j < 4; ++j) x[j] = xs[base * K + lane + 64 * j];
    z = z_seq[base * M + lane];
  }

  const float4* wrow = (const float4*)&Wz_s[lane][0];  // lane*272 B, 16-al.
  const float4* trow = (const float4*)&tz_s[wave][0];

  for (int tt = 0; tt < TAU; ++tt) {
    const int t = t0 + tt;
    // z update: z += (tanh(z) @ Wz^T - z)/100
    const float tz = tanh_fast(z);
    tz_s[wave][lane] = tz;  // wave-private row; intra-wave DS order suffices
    float zacc = 0.f;
#pragma unroll
    for (int j = 0; j < 16; ++j) {
      const float4 w = wrow[j], tv = trow[j];
      zacc += w.x * tv.x + w.y * tv.y + w.z * tv.z + w.w * tv.w;
    }
    const float znew = z + (zacc - z) * INV_TAU_Z;

    // s = sigmoid(z_new @ Az^T + b)  — DPP/swizzle butterfly reduce
    float s[R];
#pragma unroll
    for (int r = 0; r < R; ++r) s[r] = znew * azw[r];
    allreduce8(s);
#pragma unroll
    for (int r = 0; r < R; ++r) s[r] = sigmoid_fast(s[r] + azb[r]);

    // x update: u = tanh(x) @ L ; v = u*s ; x += (v @ Rm^T - x)/100
    float tx4[4];
#pragma unroll
    for (int j = 0; j < 4; ++j) tx4[j] = tanh_fast(x[j]);
    float v[R];
#pragma unroll
    for (int r = 0; r < R; ++r) v[r] = 0.f;
#pragma unroll
    for (int j = 0; j < 4; ++j) {
      const int kb = (lane + 64 * j) * 8;
      const f32x4 la = *(const f32x4*)&Ls[kb];
      const f32x4 lb = *(const f32x4*)&Ls[kb + 4];
      const float txj = tx4[j];
      v[0] += txj * la[0]; v[1] += txj * la[1];
      v[2] += txj * la[2]; v[3] += txj * la[3];
      v[4] += txj * lb[0]; v[5] += txj * lb[1];
      v[6] += txj * lb[2]; v[7] += txj * lb[3];
    }
    allreduce8(v);
#pragma unroll
    for (int r = 0; r < R; ++r) v[r] *= s[r];
#pragma unroll
    for (int j = 0; j < 4; ++j) {
      const int kb = (lane + 64 * j) * 8;
      const f32x4 ra = *(const f32x4*)&Rs[kb];
      const f32x4 rb = *(const f32x4*)&Rs[kb + 4];
      const float xacc = v[0] * ra[0] + v[1] * ra[1] + v[2] * ra[2] +
                         v[3] * ra[3] + v[4] * rb[0] + v[5] * rb[1] +
                         v[6] * rb[2] + v[7] * rb[3];
      x[j] = x[j] + (xacc - x[j]) * INV_TAU_X;
    }

    if (t < T) {
      const size_t o = ((size_t)b * T + t);
#pragma unroll
      for (int j = 0; j < 4; ++j) xs[o * K + lane + 64 * j] = x[j];
      z_pred[o * M + lane] = znew;
    }
    z = znew;
  }
}

// ---------------------------------------------------------------------------
// Schedule (5 kernels):
//  ws: X0 = BT*K floats (64 MB) | Wr = split-weight blob (1.1 MB, persistent)
//  1 split8 -> Wr
//  2 F1 fused x-chain: in_seq -> ex1 -> ex2 -> ex3(-> X0 global) -> de1
//       -> de2(-> x_recon)
//  3 F2 fused z-chain: in_seq -> ez1 -> ez2 -> ez3(-> z_seq)
//  4 scan: X0 in-place (x_states) + z_pred
//  5 F3 fused pred-decoder: X0 -> de1 -> de2(-> x_pred)
// ---------------------------------------------------------------------------
extern "C" void kernel_launch(void* const* d_in, const int* in_sizes, int n_in,
                              void* d_out, int out_size, void* d_ws,
                              size_t ws_size, hipStream_t stream) {
  const float* in_seq = (const float*)d_in[0];
  const float* Lm    = (const float*)d_in[1];
  const float* Rm    = (const float*)d_in[2];
  const float* Wz    = (const float*)d_in[3];
  const float* Az_w  = (const float*)d_in[4];
  const float* Az_b  = (const float*)d_in[5];
  const float* ex1_w = (const float*)d_in[6];
  const float* ex1_b = (const float*)d_in[7];
  const float* ex2_w = (const float*)d_in[8];
  const float* ex2_b = (const float*)d_in[9];
  const float* ex3_w = (const float*)d_in[10];
  const float* ex3_b = (const float*)d_in[11];
  const float* ez1_w = (const float*)d_in[12];
  const float* ez1_b = (const float*)d_in[13];
  const float* ez2_w = (const float*)d_in[14];
  const float* ez2_b = (const float*)d_in[15];
  const float* ez3_w = (const float*)d_in[16];
  const float* ez3_b = (const float*)d_in[17];
  const float* de1_w = (const float*)d_in[18];
  const float* de1_b = (const float*)d_in[19];
  const float* de2_w = (const float*)d_in[20];
  const float* de2_b = (const float*)d_in[21];

  float* out = (float*)d_out;
  float* x_pred  = out;                                        // BT*P
  float* x_recon = out + (size_t)BT * P;                       // BT*P
  float* z_pred  = out + (size_t)2 * BT * P;                   // BT*M
  float* z_seq   = out + (size_t)2 * BT * P + (size_t)BT * M;  // BT*M

  float* X0 = (float*)d_ws;                      // BT*K fp32 (64 MB)
  short* Wr = (short*)(X0 + (size_t)BT * K);     // split-weight blob (1.1 MB)

  // weight offsets in Wr (shorts): hi at hoff, lo at hoff + 4*n4
  const unsigned HO_EX1 = 0,      HO_EX2 = 65536,  HO_EX3 = 196608;
  const unsigned HO_DE1 = 327680, HO_DE2 = 458752;
  const unsigned HO_EZ1 = 524288, HO_EZ2 = 540672, HO_EZ3 = 548864;

  // 1: split all 8 weights into Wr
  W8 w8;
  w8.src[0] = ex1_w; w8.hoff[0] = HO_EX1; w8.n4[0] = 8192;
  w8.src[1] = ex2_w; w8.hoff[1] = HO_EX2; w8.n4[1] = 16384;
  w8.src[2] = ex3_w; w8.hoff[2] = HO_EX3; w8.n4[2] = 16384;
  w8.src[3] = de1_w; w8.hoff[3] = HO_DE1; w8.n4[3] = 16384;
  w8.src[4] = de2_w; w8.hoff[4] = HO_DE2; w8.n4[4] = 8192;
  w8.src[5] = ez1_w; w8.hoff[5] = HO_EZ1; w8.n4[5] = 2048;
  w8.src[6] = ez2_w; w8.hoff[6] = HO_EZ2; w8.n4[6] = 1024;
  w8.src[7] = ez3_w; w8.hoff[7] = HO_EZ3; w8.n4[7] = 1024;
  split8_kernel<<<dim3(64, 8), dim3(256), 0, stream>>>(w8, Wr);

  const dim3 fgrid(BT / 64), fblk(512);

  // 2: F1 fused x-chain (5 layers)
  {
    FusedArgs a{};
    a.A0 = in_seq;
    a.Wh[0] = Wr + HO_EX1; a.Wl[0] = Wr + HO_EX1 + 32768; a.bias[0] = ex1_b;
    a.Wh[1] = Wr + HO_EX2; a.Wl[1] = Wr + HO_EX2 + 65536; a.bias[1] = ex2_b;
    a.Wh[2] = Wr + HO_EX3; a.Wl[2] = Wr + HO_EX3 + 65536; a.bias[2] = ex3_b;
    a.Wh[3] = Wr + HO_DE1; a.Wl[3] = Wr + HO_DE1 + 65536; a.bias[3] = de1_b;
    a.Wh[4] = Wr + HO_DE2; a.Wl[4] = Wr + HO_DE2 + 32768; a.bias[4] = de2_b;
    a.gout[2] = X0;        // x_seq for the scan
    a.gout[4] = x_recon;
    fused_mlp<256, 5, 128, 256, 256, 256, 256, 128>
        <<<fgrid, fblk, 0, stream>>>(a);
  }
  // 3: F2 fused z-chain (3 layers)
  {
    FusedArgs a{};
    a.A0 = in_seq;
    a.Wh[0] = Wr + HO_EZ1; a.Wl[0] = Wr + HO_EZ1 + 8192; a.bias[0] = ez1_b;
    a.Wh[1] = Wr + HO_EZ2; a.Wl[1] = Wr + HO_EZ2 + 4096; a.bias[1] = ez2_b;
    a.Wh[2] = Wr + HO_EZ3; a.Wl[2] = Wr + HO_EZ3 + 4096; a.bias[2] = ez3_b;
    a.gout[2] = z_seq;
    fused_mlp<128, 3, 128, 64, 64, 64, 0, 0><<<fgrid, fblk, 0, stream>>>(a);
  }
  // 4: scan (in-place on X0), z_pred out
  scan_kernel<<<dim3(B * NSEG / 8), dim3(512), 0, stream>>>(
      X0, z_seq, Lm, Rm, Wz, Az_w, Az_b, z_pred);
  // 5: F3 fused pred-decoder (2 layers)
  {
    FusedArgs a{};
    a.A0 = X0;
    a.Wh[0] = Wr + HO_DE1; a.Wl[0] = Wr + HO_DE1 + 65536; a.bias[0] = de1_b;
    a.Wh[1] = Wr + HO_DE2; a.Wl[1] = Wr + HO_DE2 + 32768; a.bias[1] = de2_b;
    a.gout[1] = x_pred;
    fused_mlp<256, 2, 256, 256, 128, 0, 0, 0><<<fgrid, fblk, 0, stream>>>(a);
  }
}

// Round 11
// 520.827 us; speedup vs baseline: 1.3286x; 1.1881x over previous
//
#include <hip/hip_runtime.h>
#include <math.h>

// Problem constants
constexpr int B = 32, T = 2048, P = 128, K = 256, R = 8, M = 64;
constexpr int BT = B * T;                 // 65536 rows
constexpr int TAU = 5;
constexpr int NSEG = (T + TAU - 1) / TAU; // 410 segments
constexpr float INV_TAU_X = 1.0f / 100.0f;
constexpr float INV_TAU_Z = 1.0f / 100.0f;

typedef short bf16x4 __attribute__((ext_vector_type(4)));
typedef short bf16x8 __attribute__((ext_vector_type(8)));
typedef float f32x4 __attribute__((ext_vector_type(4)));

// fp32 <-> bf16 (RNE)
static __device__ __forceinline__ short f2bf(float f) {
  unsigned u = __builtin_bit_cast(unsigned, f);
  u += 0x7FFF + ((u >> 16) & 1);
  return (short)(u >> 16);
}
static __device__ __forceinline__ float bf2f(short h) {
  unsigned u = ((unsigned)(unsigned short)h) << 16;
  return __builtin_bit_cast(float, u);
}

// fast transcendentals (v_exp + v_rcp, ~1e-6 rel — invisible vs 2e-2 thresh)
static __device__ __forceinline__ float tanh_fast(float x) {
  const float e = __expf(2.f * x);
  return 1.f - 2.f * __builtin_amdgcn_rcpf(e + 1.f);
}
static __device__ __forceinline__ float sigmoid_fast(float x) {
  return __builtin_amdgcn_rcpf(1.f + __expf(-x));
}

// ---------------------------------------------------------------------------
// 64-lane all-reduce (sum) for 8 values. Stages 1-4 are the rocPRIM-standard
// gfx9 DPP ladder (all-VALU); stage 5 = ds_swizzle 0x401F (xor16), stage 6 =
// __shfl_xor 32. NOTE: gfx950 permlane16/32_swap builtins produced wrong
// sums here (r1 fail) — semantics differ from the assumed two-reg swap.
// ---------------------------------------------------------------------------
template <int CTRL>
static __device__ __forceinline__ float dppadd(float p) {
  return p + __builtin_bit_cast(
                 float, __builtin_amdgcn_update_dpp(
                            0, __builtin_bit_cast(int, p), CTRL, 0xF, 0xF, true));
}

static __device__ __forceinline__ void allreduce8(float p[R]) {
#pragma unroll
  for (int r = 0; r < R; ++r) p[r] = dppadd<0xB1>(p[r]);   // quad_perm [1,0,3,2]
#pragma unroll
  for (int r = 0; r < R; ++r) p[r] = dppadd<0x4E>(p[r]);   // quad_perm [2,3,0,1]
#pragma unroll
  for (int r = 0; r < R; ++r) p[r] = dppadd<0x141>(p[r]);  // row_half_mirror
#pragma unroll
  for (int r = 0; r < R; ++r) p[r] = dppadd<0x140>(p[r]);  // row_mirror
#pragma unroll
  for (int r = 0; r < R; ++r)                              // xor 16 (in-half)
    p[r] += __builtin_bit_cast(float, __builtin_amdgcn_ds_swizzle(
                                          __builtin_bit_cast(int, p[r]), 0x401F));
#pragma unroll
  for (int r = 0; r < R; ++r)                              // xor 32 (cross-half)
    p[r] += __shfl_xor(p[r], 32, 64);
}

// Batched split of the 8 weight matrices into one region: weight w's hi at
// dst+hoff[w], lo at dst+hoff[w]+4*n4[w].
struct W8 {
  const float* src[8];
  unsigned hoff[8];  // in shorts
  unsigned n4[8];
};
__global__ __launch_bounds__(256) void split8_kernel(W8 p, short* __restrict__ dst) {
  const int w = blockIdx.y;
  const int i = blockIdx.x * 256 + threadIdx.x;
  if (i >= (int)p.n4[w]) return;
  const float4 v = ((const float4*)p.src[w])[i];
  const float f[4] = {v.x, v.y, v.z, v.w};
  bf16x4 ph, pl;
#pragma unroll
  for (int q = 0; q < 4; ++q) {
    ph[q] = f2bf(f[q]);
    pl[q] = f2bf(f[q] - bf2f(ph[q]));
  }
  *(bf16x4*)&dst[p.hoff[w] + i * 4] = ph;
  *(bf16x4*)&dst[p.hoff[w] + p.n4[w] * 4 + i * 4] = pl;
}

// ---------------------------------------------------------------------------
// r11: fused MLP chain + wave regrid + explicit B register prefetch.
//  r10 post-mortem: conflicts 0, VALU light, HBM 10% — but MfmaUtil stuck
//  at 13.7% and VGPR_Count=64 proved the compiler kept ZERO B loads in
//  flight across phases (acc32+B32+A16 > 64): every phase serialized as
//  [issue 8 L2 loads -> stall ~300cyc -> 24 MFMA].
//  Fix:
//  (1) wave grid 1M x 8N for KOUT>=128 (NI=4 row-tiles, JT=KOUT/128 col
//      tiles): B loads/phase 8->4, no wm-duplication of B reads (block B
//      traffic per layer halves). KOUT=64 uses 2M x 4N.
//  (2) depth-2 B prefetch: 3 rotating compile-time-indexed B slots
//      (ph%3 under full unroll -> registers, rule #20); iter ph issues
//      load(ph+2) BEFORE the A ds_reads + MFMA cluster. VGPR budget
//      acc32 + A32 + B48 = 112 <= 128 (launch_bounds(512,4)).
//  LDS activation planes unchanged from r10 ([kt64][64][64] shorts h/l,
//  slot = chunk^(row&7), 8 dwords/bank floor; stage-in/read/write all
//  consistent). MFMA order per acc element unchanged (k ascending;
//  hh,lh,hl) -> bit-identical results (absmax 0.00390625).
//  All barriers wave-uniform.
// ---------------------------------------------------------------------------
struct FusedArgs {
  const float* A0;       // global input, width K0, BT rows
  const short* Wh[5];    // split weights (hi)
  const short* Wl[5];    // split weights (lo)
  const float* bias[5];
  float* gout[5];        // optional global output per layer (nullptr = none)
};

template <int I> struct Ly { static constexpr int v = I; };

template <int MAXW, int NL, int K0, int K1, int K2, int K3, int K4, int K5>
__global__ __launch_bounds__(512, 4) void fused_mlp(FusedArgs p) {
  constexpr int Kd[6] = {K0, K1, K2, K3, K4, K5};
  __shared__ short bufh[64 * MAXW];  // [W/64][64][64] shorts, swizzled
  __shared__ short bufl[64 * MAXW];

  const int tid = threadIdx.x;
  const int wave = tid >> 6, lane = tid & 63;
  const int l16 = lane & 15, quad = lane >> 4;
  const int row0 = blockIdx.x * 64;

  // stage layer-0: global fp32 -> split bf16 h/l planes (8 floats/unit)
  constexpr int G0 = K0 / 8;
  for (int u = tid; u < 64 * G0; u += 512) {
    const int row = u / G0, g = u % G0;
    const float* gp = p.A0 + (size_t)(row0 + row) * K0 + g * 8;
    const f32x4 v0 = *(const f32x4*)gp;
    const f32x4 v1 = *(const f32x4*)(gp + 4);
    bf16x8 ph, pl;
#pragma unroll
    for (int e = 0; e < 4; ++e) {
      ph[e] = f2bf(v0[e]);
      pl[e] = f2bf(v0[e] - bf2f(ph[e]));
      ph[4 + e] = f2bf(v1[e]);
      pl[4 + e] = f2bf(v1[e] - bf2f(ph[4 + e]));
    }
    const int off = ((g >> 3) * 64 + row) * 64 + (((g & 7) ^ (row & 7)) * 8);
    *(bf16x8*)&bufh[off] = ph;
    *(bf16x8*)&bufl[off] = pl;
  }
  __syncthreads();

  auto do_layer = [&](auto lc) {
    constexpr int l = decltype(lc)::v;
    constexpr int KIN = Kd[l], KOUT = Kd[l + 1];
    constexpr int NWN = (KOUT >= 128) ? 8 : 4;  // col groups
    constexpr int NWM = 8 / NWN;                // row groups (1 or 2)
    constexpr int NI = 4 / NWM;                 // 16-row tiles per wave
    constexpr int JT = KOUT / (NWN * 16);       // 16-col tiles per wave
    constexpr int NPH = KIN / 32;               // 32-k phases
    const int wm = wave / NWN, cg = wave % NWN;
    const int cols0w = cg * (KOUT / NWN);
    const int rbase = wm * NI * 16;

    f32x4 acc[NI][JT];
#pragma unroll
    for (int i = 0; i < NI; ++i)
#pragma unroll
      for (int j = 0; j < JT; ++j) acc[i][j] = (f32x4){0.f, 0.f, 0.f, 0.f};

    // 3 rotating B prefetch slots (all indices compile-time post-unroll)
    bf16x8 bh[3][JT], bl[3][JT];
    auto loadB = [&](int ph, int slot) {
#pragma unroll
      for (int j = 0; j < JT; ++j) {
        const size_t boff =
            (size_t)(cols0w + j * 16 + l16) * KIN + ph * 32 + quad * 8;
        bh[slot][j] = *(const bf16x8*)(p.Wh[l] + boff);
        bl[slot][j] = *(const bf16x8*)(p.Wl[l] + boff);
      }
    };
    loadB(0, 0);
    if constexpr (NPH > 1) loadB(1, 1);

#pragma unroll
    for (int ph = 0; ph < NPH; ++ph) {
      // issue phase ph+2's B loads first (depth-2 in flight under MFMAs)
      if (ph + 2 < NPH) loadB(ph + 2, (ph + 2) % 3);
      // A frags straight from split LDS
      const int kt = ph >> 1;
      const int qc = (ph & 1) * 4 + quad;
      bf16x8 ah[NI], al[NI];
#pragma unroll
      for (int i = 0; i < NI; ++i) {
        const int r = rbase + i * 16 + l16;
        const int off = (kt * 64 + r) * 64 + ((qc ^ (r & 7)) * 8);
        ah[i] = *(const bf16x8*)&bufh[off];
        al[i] = *(const bf16x8*)&bufl[off];
      }
      const int s = ph % 3;
#pragma unroll
      for (int j = 0; j < JT; ++j)
#pragma unroll
        for (int i = 0; i < NI; ++i) {
          acc[i][j] = __builtin_amdgcn_mfma_f32_16x16x32_bf16(
              ah[i], bh[s][j], acc[i][j], 0, 0, 0);
          acc[i][j] = __builtin_amdgcn_mfma_f32_16x16x32_bf16(
              al[i], bh[s][j], acc[i][j], 0, 0, 0);
          acc[i][j] = __builtin_amdgcn_mfma_f32_16x16x32_bf16(
              ah[i], bl[s][j], acc[i][j], 0, 0, 0);
        }
    }
    if constexpr (l < NL - 1) __syncthreads();  // all A reads done

    // epilogue: tanh; split ONCE at production -> LDS planes and/or global
    float* gout = p.gout[l];
#pragma unroll
    for (int j = 0; j < JT; ++j) {
      const int col = cols0w + j * 16 + l16;
      const float bj = p.bias[l][col];
#pragma unroll
      for (int i = 0; i < NI; ++i) {
#pragma unroll
        for (int r = 0; r < 4; ++r) {
          const float v = tanh_fast(acc[i][j][r] + bj);
          const int row = rbase + i * 16 + quad * 4 + r;
          if constexpr (l < NL - 1) {
            const int off = ((col >> 6) * 64 + row) * 64 +
                            ((((col & 63) >> 3) ^ (row & 7)) * 8) + (col & 7);
            const short h = f2bf(v);
            bufh[off] = h;
            bufl[off] = f2bf(v - bf2f(h));
          }
          if (gout) gout[(size_t)(row0 + row) * KOUT + col] = v;
        }
      }
    }
    if constexpr (l < NL - 1) __syncthreads();  // next A ready
  };

  do_layer(Ly<0>{});
  if constexpr (NL > 1) do_layer(Ly<1>{});
  if constexpr (NL > 2) do_layer(Ly<2>{});
  if constexpr (NL > 3) do_layer(Ly<3>{});
  if constexpr (NL > 4) do_layer(Ly<4>{});
}

// ---------------------------------------------------------------------------
// Scan: unchanged from r6 (proven, ~78 µs). Reset every TAU=5 -> independent
// (batch, segment) chains; one wave per chain, 8 waves/block, no inner
// barriers. fp32 x in-place on X0.
// ---------------------------------------------------------------------------
__global__ __launch_bounds__(512) void scan_kernel(
    float* xs,                                 // fp32 x_seq / x_states (in-place)
    const float* __restrict__ z_seq,           // fp32
    const float* __restrict__ Lm, const float* __restrict__ Rm,
    const float* __restrict__ Wz, const float* __restrict__ Az_w,
    const float* __restrict__ Az_b,
    float* __restrict__ z_pred) {
  __shared__ __align__(16) float Wz_s[M][68];  // stride 68: 16B rows, balanced
  __shared__ __align__(16) float Ls[K * R];    // native [k][r] layout
  __shared__ __align__(16) float Rs[K * R];    // native [k][r] layout
  __shared__ __align__(16) float tz_s[8][M];   // per-wave rows (256 B aligned)

  const int tid = threadIdx.x;
  for (int i = tid; i < M * M; i += 512) Wz_s[i >> 6][i & 63] = Wz[i];
  // K*R = 2048 floats = 512 float4 -> exactly one per thread
  ((float4*)Ls)[tid] = ((const float4*)Lm)[tid];
  ((float4*)Rs)[tid] = ((const float4*)Rm)[tid];
  __syncthreads();

  const int wave = tid >> 6;
  const int lane = tid & 63;
  const int chain = blockIdx.x * 8 + wave;
  const int b = chain / NSEG;
  const int seg = chain % NSEG;
  const int t0 = seg * TAU;

  // per-lane register caches (reused all 5 steps)
  float azw[R], azb[R];
#pragma unroll
  for (int r = 0; r < R; ++r) {
    azw[r] = Az_w[r * M + lane];
    azb[r] = Az_b[r];
  }

  float x[4], z;
  {
    const size_t base = ((size_t)b * T + t0);
#pragma unroll
    for (int j = 0; j < 4; ++j) x[j] = xs[base * K + lane + 64 * j];
    z = z_seq[base * M + lane];
  }

  const float4* wrow = (const float4*)&Wz_s[lane][0];  // lane*272 B, 16-al.
  const float4* trow = (const float4*)&tz_s[wave][0];

  for (int tt = 0; tt < TAU; ++tt) {
    const int t = t0 + tt;
    // z update: z += (tanh(z) @ Wz^T - z)/100
    const float tz = tanh_fast(z);
    tz_s[wave][lane] = tz;  // wave-private row; intra-wave DS order suffices
    float zacc = 0.f;
#pragma unroll
    for (int j = 0; j < 16; ++j) {
      const float4 w = wrow[j], tv = trow[j];
      zacc += w.x * tv.x + w.y * tv.y + w.z * tv.z + w.w * tv.w;
    }
    const float znew = z + (zacc - z) * INV_TAU_Z;

    // s = sigmoid(z_new @ Az^T + b)  — DPP/swizzle butterfly reduce
    float s[R];
#pragma unroll
    for (int r = 0; r < R; ++r) s[r] = znew * azw[r];
    allreduce8(s);
#pragma unroll
    for (int r = 0; r < R; ++r) s[r] = sigmoid_fast(s[r] + azb[r]);

    // x update: u = tanh(x) @ L ; v = u*s ; x += (v @ Rm^T - x)/100
    float tx4[4];
#pragma unroll
    for (int j = 0; j < 4; ++j) tx4[j] = tanh_fast(x[j]);
    float v[R];
#pragma unroll
    for (int r = 0; r < R; ++r) v[r] = 0.f;
#pragma unroll
    for (int j = 0; j < 4; ++j) {
      const int kb = (lane + 64 * j) * 8;
      const f32x4 la = *(const f32x4*)&Ls[kb];
      const f32x4 lb = *(const f32x4*)&Ls[kb + 4];
      const float txj = tx4[j];
      v[0] += txj * la[0]; v[1] += txj * la[1];
      v[2] += txj * la[2]; v[3] += txj * la[3];
      v[4] += txj * lb[0]; v[5] += txj * lb[1];
      v[6] += txj * lb[2]; v[7] += txj * lb[3];
    }
    allreduce8(v);
#pragma unroll
    for (int r = 0; r < R; ++r) v[r] *= s[r];
#pragma unroll
    for (int j = 0; j < 4; ++j) {
      const int kb = (lane + 64 * j) * 8;
      const f32x4 ra = *(const f32x4*)&Rs[kb];
      const f32x4 rb = *(const f32x4*)&Rs[kb + 4];
      const float xacc = v[0] * ra[0] + v[1] * ra[1] + v[2] * ra[2] +
                         v[3] * ra[3] + v[4] * rb[0] + v[5] * rb[1] +
                         v[6] * rb[2] + v[7] * rb[3];
      x[j] = x[j] + (xacc - x[j]) * INV_TAU_X;
    }

    if (t < T) {
      const size_t o = ((size_t)b * T + t);
#pragma unroll
      for (int j = 0; j < 4; ++j) xs[o * K + lane + 64 * j] = x[j];
      z_pred[o * M + lane] = znew;
    }
    z = znew;
  }
}

// ---------------------------------------------------------------------------
// Schedule (5 kernels):
//  ws: X0 = BT*K floats (64 MB) | Wr = split-weight blob (1.1 MB, persistent)
//  1 split8 -> Wr
//  2 F1 fused x-chain: in_seq -> ex1 -> ex2 -> ex3(-> X0 global) -> de1
//       -> de2(-> x_recon)
//  3 F2 fused z-chain: in_seq -> ez1 -> ez2 -> ez3(-> z_seq)
//  4 scan: X0 in-place (x_states) + z_pred
//  5 F3 fused pred-decoder: X0 -> de1 -> de2(-> x_pred)
// ---------------------------------------------------------------------------
extern "C" void kernel_launch(void* const* d_in, const int* in_sizes, int n_in,
                              void* d_out, int out_size, void* d_ws,
                              size_t ws_size, hipStream_t stream) {
  const float* in_seq = (const float*)d_in[0];
  const float* Lm    = (const float*)d_in[1];
  const float* Rm    = (const float*)d_in[2];
  const float* Wz    = (const float*)d_in[3];
  const float* Az_w  = (const float*)d_in[4];
  const float* Az_b  = (const float*)d_in[5];
  const float* ex1_w = (const float*)d_in[6];
  const float* ex1_b = (const float*)d_in[7];
  const float* ex2_w = (const float*)d_in[8];
  const float* ex2_b = (const float*)d_in[9];
  const float* ex3_w = (const float*)d_in[10];
  const float* ex3_b = (const float*)d_in[11];
  const float* ez1_w = (const float*)d_in[12];
  const float* ez1_b = (const float*)d_in[13];
  const float* ez2_w = (const float*)d_in[14];
  const float* ez2_b = (const float*)d_in[15];
  const float* ez3_w = (const float*)d_in[16];
  const float* ez3_b = (const float*)d_in[17];
  const float* de1_w = (const float*)d_in[18];
  const float* de1_b = (const float*)d_in[19];
  const float* de2_w = (const float*)d_in[20];
  const float* de2_b = (const float*)d_in[21];

  float* out = (float*)d_out;
  float* x_pred  = out;                                        // BT*P
  float* x_recon = out + (size_t)BT * P;                       // BT*P
  float* z_pred  = out + (size_t)2 * BT * P;                   // BT*M
  float* z_seq   = out + (size_t)2 * BT * P + (size_t)BT * M;  // BT*M

  float* X0 = (float*)d_ws;                      // BT*K fp32 (64 MB)
  short* Wr = (short*)(X0 + (size_t)BT * K);     // split-weight blob (1.1 MB)

  // weight offsets in Wr (shorts): hi at hoff, lo at hoff + 4*n4
  const unsigned HO_EX1 = 0,      HO_EX2 = 65536,  HO_EX3 = 196608;
  const unsigned HO_DE1 = 327680, HO_DE2 = 458752;
  const unsigned HO_EZ1 = 524288, HO_EZ2 = 540672, HO_EZ3 = 548864;

  // 1: split all 8 weights into Wr
  W8 w8;
  w8.src[0] = ex1_w; w8.hoff[0] = HO_EX1; w8.n4[0] = 8192;
  w8.src[1] = ex2_w; w8.hoff[1] = HO_EX2; w8.n4[1] = 16384;
  w8.src[2] = ex3_w; w8.hoff[2] = HO_EX3; w8.n4[2] = 16384;
  w8.src[3] = de1_w; w8.hoff[3] = HO_DE1; w8.n4[3] = 16384;
  w8.src[4] = de2_w; w8.hoff[4] = HO_DE2; w8.n4[4] = 8192;
  w8.src[5] = ez1_w; w8.hoff[5] = HO_EZ1; w8.n4[5] = 2048;
  w8.src[6] = ez2_w; w8.hoff[6] = HO_EZ2; w8.n4[6] = 1024;
  w8.src[7] = ez3_w; w8.hoff[7] = HO_EZ3; w8.n4[7] = 1024;
  split8_kernel<<<dim3(64, 8), dim3(256), 0, stream>>>(w8, Wr);

  const dim3 fgrid(BT / 64), fblk(512);

  // 2: F1 fused x-chain (5 layers)
  {
    FusedArgs a{};
    a.A0 = in_seq;
    a.Wh[0] = Wr + HO_EX1; a.Wl[0] = Wr + HO_EX1 + 32768; a.bias[0] = ex1_b;
    a.Wh[1] = Wr + HO_EX2; a.Wl[1] = Wr + HO_EX2 + 65536; a.bias[1] = ex2_b;
    a.Wh[2] = Wr + HO_EX3; a.Wl[2] = Wr + HO_EX3 + 65536; a.bias[2] = ex3_b;
    a.Wh[3] = Wr + HO_DE1; a.Wl[3] = Wr + HO_DE1 + 65536; a.bias[3] = de1_b;
    a.Wh[4] = Wr + HO_DE2; a.Wl[4] = Wr + HO_DE2 + 32768; a.bias[4] = de2_b;
    a.gout[2] = X0;        // x_seq for the scan
    a.gout[4] = x_recon;
    fused_mlp<256, 5, 128, 256, 256, 256, 256, 128>
        <<<fgrid, fblk, 0, stream>>>(a);
  }
  // 3: F2 fused z-chain (3 layers)
  {
    FusedArgs a{};
    a.A0 = in_seq;
    a.Wh[0] = Wr + HO_EZ1; a.Wl[0] = Wr + HO_EZ1 + 8192; a.bias[0] = ez1_b;
    a.Wh[1] = Wr + HO_EZ2; a.Wl[1] = Wr + HO_EZ2 + 4096; a.bias[1] = ez2_b;
    a.Wh[2] = Wr + HO_EZ3; a.Wl[2] = Wr + HO_EZ3 + 4096; a.bias[2] = ez3_b;
    a.gout[2] = z_seq;
    fused_mlp<128, 3, 128, 64, 64, 64, 0, 0><<<fgrid, fblk, 0, stream>>>(a);
  }
  // 4: scan (in-place on X0), z_pred out
  scan_kernel<<<dim3(B * NSEG / 8), dim3(512), 0, stream>>>(
      X0, z_seq, Lm, Rm, Wz, Az_w, Az_b, z_pred);
  // 5: F3 fused pred-decoder (2 layers)
  {
    FusedArgs a{};
    a.A0 = X0;
    a.Wh[0] = Wr + HO_DE1; a.Wl[0] = Wr + HO_DE1 + 65536; a.bias[0] = de1_b;
    a.Wh[1] = Wr + HO_DE2; a.Wl[1] = Wr + HO_DE2 + 32768; a.bias[1] = de2_b;
    a.gout[1] = x_pred;
    fused_mlp<256, 2, 256, 256, 128, 0, 0, 0><<<fgrid, fblk, 0, stream>>>(a);
  }
}